// Round 2
// baseline (1009.934 us; speedup 1.0000x reference)
//
#include <hip/hip_runtime.h>

// QORNN eval forward: quantized RNN scan, B=256 T=128 I=128 H=1024 O=10.
// Strategy: quantized weights/inputs are EXACT in bf16 -> MFMA bf16 with fp32
// accum; h carried as split bf16 pair (hh+hl, ~17 mantissa bits).
// 128 per-step GEMM launches (graph-captured), ping-pong h buffers.

#define BB 256
#define TT 128
#define II 128
#define HH 1024
#define OO 10
#define EPSF 1e-5f

typedef short bf16x8 __attribute__((ext_vector_type(8)));
typedef float f32x4 __attribute__((ext_vector_type(4)));
typedef unsigned int u32x4 __attribute__((ext_vector_type(4)));

static __device__ __forceinline__ unsigned short f2bf(float f) {
  union { float f; unsigned u; } v; v.f = f;
  unsigned r = v.u + 0x7fffu + ((v.u >> 16) & 1u);
  return (unsigned short)(r >> 16);
}
static __device__ __forceinline__ float bf2f(unsigned short b) {
  union { unsigned u; float f; } v; v.u = ((unsigned)b) << 16;
  return v.f;
}
// jnp.round is round-half-to-EVEN -> rintf (v_rndne_f32), NOT roundf.
static __device__ __forceinline__ float q8(float x) {
  return fminf(fmaxf(__builtin_rintf(x * 128.f), -128.f), 127.f) * 0.0078125f;
}
static __device__ __forceinline__ float q4(float x) {
  return fminf(fmaxf(__builtin_rintf(x * 8.f), -8.f), 7.f) * 0.125f;
}

// ---------------- prep: quantize inputs to bf16, layout [T][B][I] ----------
__global__ __launch_bounds__(256) void k_quant_x(const float* __restrict__ in,
                                                 unsigned short* __restrict__ xq) {
  int idx = blockIdx.x * 256 + threadIdx.x;   // 1,048,576 threads, 4 elems each
  int n = idx * 4;                            // linear over [T][B][I]
  int i = n & (II - 1);
  int rem = n >> 7;                           // t*BB + b
  int b = rem & (BB - 1);
  int t = rem >> 8;
  const float4 v = *reinterpret_cast<const float4*>(in + ((size_t)b * TT + t) * II + i);
  ushort4 o;
  o.x = f2bf(q8(v.x)); o.y = f2bf(q8(v.y)); o.z = f2bf(q8(v.z)); o.w = f2bf(q8(v.w));
  *reinterpret_cast<ushort4*>(xq + n) = o;
}

// ------- prep: quantize Wr/Wi to bf16, zero h0, fold norm scales -----------
__global__ __launch_bounds__(256) void k_prep(
    const float* __restrict__ Wi, const float* __restrict__ Wr,
    const float* __restrict__ bi, const float* __restrict__ br,
    const float* __restrict__ nig, const float* __restrict__ nib,
    const float* __restrict__ nirm, const float* __restrict__ nirv,
    const float* __restrict__ nrg, const float* __restrict__ nrb,
    const float* __restrict__ nrrm, const float* __restrict__ nrrv,
    unsigned short* __restrict__ wiq, unsigned short* __restrict__ wrq,
    unsigned short* __restrict__ hbuf0, float* __restrict__ svec) {
  int id = blockIdx.x * 256 + threadIdx.x;
  if (id < 262144) {                       // Wr: 1,048,576 elems, q8
    int e = id * 4;
    const float4 v = *reinterpret_cast<const float4*>(Wr + e);
    ushort4 o;
    o.x = f2bf(q8(v.x)); o.y = f2bf(q8(v.y)); o.z = f2bf(q8(v.z)); o.w = f2bf(q8(v.w));
    *reinterpret_cast<ushort4*>(wrq + e) = o;
  } else if (id < 294912) {                // Wi: 131,072 elems, q4
    int e = (id - 262144) * 4;
    const float4 v = *reinterpret_cast<const float4*>(Wi + e);
    ushort4 o;
    o.x = f2bf(q4(v.x)); o.y = f2bf(q4(v.y)); o.z = f2bf(q4(v.z)); o.w = f2bf(q4(v.w));
    *reinterpret_cast<ushort4*>(wiq + e) = o;
  } else if (id < 360448) {                // zero h0 (1 MB = 65,536 x 16B)
    int e = id - 294912;
    u32x4 z = {0u, 0u, 0u, 0u};
    reinterpret_cast<u32x4*>(hbuf0)[e] = z;
  } else if (id < 361472) {                // folded norm scales
    int j = id - 360448;
    float si = nig[j] / sqrtf(nirv[j] + EPSF);
    float ti = nib[j] - nirm[j] * si;
    float sr = nrg[j] / sqrtf(nrrv[j] + EPSF);
    float tr = nrb[j] - nrrm[j] * sr;
    svec[j] = si;
    svec[HH + j] = sr;
    svec[2 * HH + j] = si * bi[j] + ti + sr * br[j] + tr;
  }
}

// ---------------- one RNN step: h_out = tanh(si*xWi^T + sr*hWr^T + c) ------
// grid (16,16): blockIdx.x = b-tile (16 rows), blockIdx.y = j-tile (64 cols)
// block 256 thr = 4 waves, each wave one 16x16 MFMA tile.
__global__ __launch_bounds__(256) void k_step(
    const unsigned short* __restrict__ xq,   // [T][B][I] bf16 (exact)
    const unsigned short* __restrict__ wiq,  // [H][I]  bf16 (exact)
    const unsigned short* __restrict__ wrq,  // [H][H]  bf16 (exact)
    const float* __restrict__ svec,          // si[H], sr[H], c[H]
    const unsigned short* __restrict__ hin,  // hh[B][H], hl[B][H]
    unsigned short* __restrict__ hout,
    int t) {
  __shared__ __align__(16) unsigned char smem[65536];  // hh 32KB @0, hl 32KB @32768
  const int tid = threadIdx.x;
  const int br0 = blockIdx.x * 16;
  const int by = blockIdx.y;

  const unsigned short* hinh = hin;
  const unsigned short* hinl = hin + BB * HH;

  // Stage h pair [16][1024] bf16 into LDS, XOR-swizzled (kills 2048B-stride
  // bank conflict on the ds_read_b128 fragment reads).
#pragma unroll
  for (int r = 0; r < 8; ++r) {
    int e = (r * 256 + tid) * 8;
    int row = e >> 10, col = e & 1023;
    u32x4 vh = *reinterpret_cast<const u32x4*>(hinh + (br0 + row) * HH + col);
    u32x4 vl = *reinterpret_cast<const u32x4*>(hinl + (br0 + row) * HH + col);
    int byteo = row * 2048 + ((col * 2) ^ ((row & 7) << 4));
    *reinterpret_cast<u32x4*>(smem + byteo) = vh;
    *reinterpret_cast<u32x4*>(smem + 32768 + byteo) = vl;
  }

  const int w = tid >> 6, lane = tid & 63;
  const int ar = lane & 15;                 // A-frag row (b within tile)
  const int khalf = (lane >> 4) * 8;        // A/B frag k-offset
  const int jrow = by * 64 + w * 16 + (lane & 15);  // B-frag row = output col j

  f32x4 acc_i = {0.f, 0.f, 0.f, 0.f};
  f32x4 acc_r = {0.f, 0.f, 0.f, 0.f};

  // Input part first, K=128 (no LDS dependence -> overlaps staging drain)
#pragma unroll
  for (int kk = 0; kk < II; kk += 32) {
    int col0 = kk + khalf;
    bf16x8 ax = *reinterpret_cast<const bf16x8*>(
        xq + ((size_t)t * BB + br0 + ar) * II + col0);
    bf16x8 bw = *reinterpret_cast<const bf16x8*>(wiq + jrow * II + col0);
    acc_i = __builtin_amdgcn_mfma_f32_16x16x32_bf16(ax, bw, acc_i, 0, 0, 0);
  }

  __syncthreads();

  // Recurrent part, K=1024: acc_r += hh*Wr + hl*Wr (split-h, ~fp32 accurate)
#pragma unroll 4
  for (int kk = 0; kk < HH; kk += 32) {
    int col0 = kk + khalf;
    int abyte = ar * 2048 + ((col0 * 2) ^ ((ar & 7) << 4));
    bf16x8 ahh = *reinterpret_cast<const bf16x8*>(smem + abyte);
    bf16x8 ahl = *reinterpret_cast<const bf16x8*>(smem + 32768 + abyte);
    bf16x8 bw = *reinterpret_cast<const bf16x8*>(wrq + jrow * HH + col0);
    acc_r = __builtin_amdgcn_mfma_f32_16x16x32_bf16(ahh, bw, acc_r, 0, 0, 0);
    acc_r = __builtin_amdgcn_mfma_f32_16x16x32_bf16(ahl, bw, acc_r, 0, 0, 0);
  }

  // Epilogue: C/D layout col = lane&15 (=j), row = (lane>>4)*4 + v (=b)
  const float si = svec[jrow];
  const float sr = svec[HH + jrow];
  const float cj = svec[2 * HH + jrow];
  unsigned short* houth = hout;
  unsigned short* houtl = hout + BB * HH;
  const int brow0 = br0 + (lane >> 4) * 4;
#pragma unroll
  for (int v = 0; v < 4; ++v) {
    float val = si * acc_i[v] + sr * acc_r[v] + cj;
    float hv = tanhf(val);
    unsigned short hb = f2bf(hv);
    float lo = hv - bf2f(hb);
    unsigned short lb = f2bf(lo);
    houth[(size_t)(brow0 + v) * HH + jrow] = hb;
    houtl[(size_t)(brow0 + v) * HH + jrow] = lb;
  }
}

// ---------------- output: out[b][o] = so*(h . q4(Wo[o])) + to --------------
__global__ __launch_bounds__(256) void k_out(
    const unsigned short* __restrict__ hfin,  // hh[B][H], hl[B][H]
    const float* __restrict__ Wo,
    const float* __restrict__ nog, const float* __restrict__ nob,
    const float* __restrict__ norm_, const float* __restrict__ norv,
    float* __restrict__ out) {
  const int b = blockIdx.x, tid = threadIdx.x;
  __shared__ float lp[4][OO];
  float hv[4];
#pragma unroll
  for (int u = 0; u < 4; ++u) {
    int k = tid * 4 + u;
    hv[u] = bf2f(hfin[b * HH + k]) + bf2f(hfin[BB * HH + b * HH + k]);
  }
  float pacc[OO];
#pragma unroll
  for (int o = 0; o < OO; ++o) {
    float p = 0.f;
#pragma unroll
    for (int u = 0; u < 4; ++u) {
      int k = tid * 4 + u;
      p += hv[u] * q4(Wo[o * HH + k]);
    }
    pacc[o] = p;
  }
#pragma unroll
  for (int o = 0; o < OO; ++o) {
    float p = pacc[o];
    for (int off = 32; off > 0; off >>= 1) p += __shfl_down(p, off);
    if ((tid & 63) == 0) lp[tid >> 6][o] = p;
  }
  __syncthreads();
  if (tid < OO) {
    float s = lp[0][tid] + lp[1][tid] + lp[2][tid] + lp[3][tid];
    float so = nog[tid] / sqrtf(norv[tid] + EPSF);
    float to = nob[tid] - norm_[tid] * so;
    out[b * OO + tid] = s * so + to;
  }
}

// ---------------------------------------------------------------------------
extern "C" void kernel_launch(void* const* d_in, const int* in_sizes, int n_in,
                              void* d_out, int out_size, void* d_ws, size_t ws_size,
                              hipStream_t stream) {
  const float* inputs = (const float*)d_in[0];
  const float* Wi = (const float*)d_in[1];
  const float* bi = (const float*)d_in[2];
  const float* Wr = (const float*)d_in[3];
  const float* br = (const float*)d_in[4];
  const float* Wo = (const float*)d_in[5];
  const float* ni_g = (const float*)d_in[6];
  const float* ni_b = (const float*)d_in[7];
  const float* ni_rm = (const float*)d_in[8];
  const float* ni_rv = (const float*)d_in[9];
  const float* nr_g = (const float*)d_in[10];
  const float* nr_b = (const float*)d_in[11];
  const float* nr_rm = (const float*)d_in[12];
  const float* nr_rv = (const float*)d_in[13];
  const float* no_g = (const float*)d_in[14];
  const float* no_b = (const float*)d_in[15];
  const float* no_rm = (const float*)d_in[16];
  const float* no_rv = (const float*)d_in[17];

  char* ws = (char*)d_ws;
  unsigned short* xq = (unsigned short*)(ws + 0);          // 8,388,608 B
  unsigned short* wiq = (unsigned short*)(ws + 8388608);   //   262,144 B
  unsigned short* wrq = (unsigned short*)(ws + 8650752);   // 2,097,152 B
  unsigned short* hb0 = (unsigned short*)(ws + 10747904);  // 1,048,576 B
  unsigned short* hb1 = (unsigned short*)(ws + 11796480);  // 1,048,576 B
  float* svec = (float*)(ws + 12845056);                   //    12,288 B

  k_quant_x<<<4096, 256, 0, stream>>>(inputs, xq);
  k_prep<<<1412, 256, 0, stream>>>(Wi, Wr, bi, br, ni_g, ni_b, ni_rm, ni_rv,
                                   nr_g, nr_b, nr_rm, nr_rv, wiq, wrq, hb0, svec);

  unsigned short* hb[2] = {hb0, hb1};
  for (int t = 0; t < TT; ++t) {
    k_step<<<dim3(16, 16), 256, 0, stream>>>(xq, wiq, wrq, svec,
                                             hb[t & 1], hb[(t + 1) & 1], t);
  }
  // T=128 even -> final h lives in hb0
  k_out<<<BB, 256, 0, stream>>>(hb0, Wo, no_g, no_b, no_rm, no_rv, (float*)d_out);
}